// Round 15
// baseline (127.940 us; speedup 1.0000x reference)
//
#include <hip/hip_runtime.h>

typedef unsigned short u16;
typedef __attribute__((ext_vector_type(8))) short bf16x8;   // 8 bf16 in 4 VGPRs
typedef __attribute__((ext_vector_type(4))) float f32x4;
typedef __attribute__((ext_vector_type(16))) float f32x16;
typedef __attribute__((ext_vector_type(4))) int i32x4;

typedef const __attribute__((address_space(1))) void gvoid_t;
typedef __attribute__((address_space(3))) void svoid_t;

// fp32 -> bf16 round-to-nearest-even
__device__ __forceinline__ u16 f2bf(float f) {
  unsigned u = __builtin_bit_cast(unsigned, f);
  u += 0x7fffu + ((u >> 16) & 1u);
  return (u16)(u >> 16);
}

// packed f32 pair -> 2xbf16 in one u32 (lo=a, hi=b)
__device__ __forceinline__ unsigned cvtpk(float a, float b) {
  unsigned r;
  asm("v_cvt_pk_bf16_f32 %0, %1, %2" : "=v"(r) : "v"(a), "v"(b));
  return r;
}

// async global->LDS, 16B per lane; lds base wave-uniform (HW adds lane*16)
__device__ __forceinline__ void gload_lds16(const u16* g, u16* ldsbase) {
  __builtin_amdgcn_global_load_lds((gvoid_t*)g, (svoid_t*)ldsbase, 16, 0, 0);
}

__device__ __forceinline__ void mfma16(f32x4& d, bf16x8 a, bf16x8 b) {
  asm("v_mfma_f32_16x16x32_bf16 %0, %1, %2, %0" : "+v"(d) : "v"(a), "v"(b));
}
__device__ __forceinline__ void mfma32(f32x16& d, bf16x8 a, bf16x8 b) {
  asm("v_mfma_f32_32x32x16_bf16 %0, %1, %2, %0" : "+v"(d) : "v"(a), "v"(b));
}
__device__ __forceinline__ void mfma_fence4(f32x4& a, f32x4& b, f32x4& c, f32x4& d) {
  asm volatile("s_nop 7\n\ts_nop 7" : "+v"(a), "+v"(b), "+v"(c), "+v"(d));
}
__device__ __forceinline__ void fence16x2(f32x16& a, f32x16& b) {
  asm volatile("s_nop 7\n\ts_nop 7\n\ts_nop 7" : "+v"(a), "+v"(b));
}

// ---------------- conversions (weights only; x handled inside g1) -----------
struct W8 { const float* s[8]; };
__global__ __launch_bounds__(256) void cvt_w_kernel(W8 w, u16* __restrict__ wb) {
  const int b = blockIdx.x;
  const int wi = b >> 7;
  const int wo = b & 127;
  const float* src = w.s[wi];
  u16* dst = wb + (size_t)wi * 131072;
  int i = (wo * 256 + (int)threadIdx.x) * 4;
  float4 v = *(const float4*)(src + i);
  ushort4 o = {f2bf(v.x), f2bf(v.y), f2bf(v.z), f2bf(v.w)};
  *(ushort4*)(dst + i) = o;
}

// ---------------- NT GEMM: C[m][n] = sum_k A[m][k] * B[n][k] ----------------
// BM x 128 tile, BK=64, 4 waves, double-buffered XOR-swizzled LDS.
// BM=128: waves 2x2 (each 64x64, 4x4 frags). BM=64: waves 1x4 (each 64x32,
// 4x2 frags). osc[z]: output scale. vt[z]: write bf16 output transposed into
// [b*16+h][d][t=2048] layout. CVTA (BM=64 only): A is fp32; staging is
// reg-staged load -> cvt_pk -> ds_write (layout byte-identical to
// gload_lds16), eliminating the bf16-x roundtrip.
struct G3 { const u16* A[3]; const u16* B[3]; void* C[3]; float osc[3]; int vt[3]; };

template <typename OutT, int BM, bool CVTA>
__global__ __launch_bounds__(256) void gemm_nt(G3 g, int M, int N, int K) {
  constexpr int NI = (BM == 128) ? 4 : 2;   // n-frags per wave
  __shared__ __align__(16) u16 At[2][BM * 64];
  __shared__ __align__(16) u16 Bt[2][128 * 64];
  const int z = blockIdx.z;
  const u16* __restrict__ A = g.A[z];
  const float* __restrict__ Af = (const float*)g.A[z];
  const u16* __restrict__ Bw = g.B[z];
  const float osc = g.osc[z];
  const int tid = threadIdx.x;
  const int lane = tid & 63, w = tid >> 6;
  const int wm = (BM == 128) ? (w >> 1) : 0;
  const int wn = (BM == 128) ? (w & 1) : w;
  constexpr int WNW = (BM == 128) ? 64 : 32;  // wave n-width
  const int l15 = lane & 15, l4 = lane >> 4;
  const int row0 = blockIdx.x * BM, col0 = blockIdx.y * 128;
  const int srow = lane >> 3;
  const int schunk = ((lane & 7) ^ srow) * 8;
  const u16* Ag = A + (size_t)(row0 + w * 8 + srow) * K + schunk;
  const u16* Bg = Bw + (size_t)(col0 + w * 8 + srow) * K + schunk;
  f32x4 acc[4][NI] = {};
  float4 ax[4];  // CVTA staging regs (BM=64: 2 instrs x 2 float4)
  auto STAGEB = [&](int k0, int buf) {
#pragma unroll
    for (int i = 0; i < 4; ++i)
      gload_lds16(Bg + (size_t)i * 32 * K + k0, &Bt[buf][(w * 8 + i * 32) * 64]);
  };
  auto STAGEA_G = [&](int k0, int buf) {
#pragma unroll
    for (int i = 0; i < BM / 32; ++i)
      gload_lds16(Ag + (size_t)i * 32 * K + k0, &At[buf][(w * 8 + i * 32) * 64]);
  };
  auto LOADA = [&](int k0) {  // CVTA: issue fp32 loads (held in regs)
#pragma unroll
    for (int i = 0; i < BM / 32; ++i) {
      const float* src = Af + (size_t)(row0 + w * 8 + i * 32 + srow) * K + k0 + schunk;
      ax[2 * i] = *(const float4*)src;
      ax[2 * i + 1] = *(const float4*)(src + 4);
    }
  };
  auto WRITEA = [&](int buf) {  // CVTA: cvt + ds_write (same layout as gload)
#pragma unroll
    for (int i = 0; i < BM / 32; ++i) {
      i32x4 d;
      d[0] = (int)cvtpk(ax[2 * i].x, ax[2 * i].y);
      d[1] = (int)cvtpk(ax[2 * i].z, ax[2 * i].w);
      d[2] = (int)cvtpk(ax[2 * i + 1].x, ax[2 * i + 1].y);
      d[3] = (int)cvtpk(ax[2 * i + 1].z, ax[2 * i + 1].w);
      *(i32x4*)&At[buf][(w * 8 + i * 32 + srow) * 64 + (lane & 7) * 8] = d;
    }
  };
  if constexpr (CVTA) LOADA(0); else STAGEA_G(0, 0);
  STAGEB(0, 0);
  if constexpr (CVTA) WRITEA(0);
  asm volatile("s_waitcnt vmcnt(0)" ::: "memory");
  __syncthreads();
  const int nk = K >> 6;
  for (int t = 0; t < nk; ++t) {
    const int cur = t & 1;
    if (t + 1 < nk) {
      if constexpr (CVTA) LOADA((t + 1) << 6); else STAGEA_G((t + 1) << 6, cur ^ 1);
      STAGEB((t + 1) << 6, cur ^ 1);
    }
#pragma unroll
    for (int kk = 0; kk < 64; kk += 32) {
      bf16x8 af[4], bfr[NI];
#pragma unroll
      for (int mi = 0; mi < 4; ++mi) {
        const int r = wm * 64 + mi * 16 + l15;
        af[mi] = *(const bf16x8*)&At[cur][r * 64 + ((kk + 8 * l4) ^ ((r & 7) << 3))];
      }
#pragma unroll
      for (int ni = 0; ni < NI; ++ni) {
        const int r = wn * WNW + ni * 16 + l15;
        bfr[ni] = *(const bf16x8*)&Bt[cur][r * 64 + ((kk + 8 * l4) ^ ((r & 7) << 3))];
      }
#pragma unroll
      for (int mi = 0; mi < 4; ++mi)
#pragma unroll
        for (int ni = 0; ni < NI; ++ni) mfma16(acc[mi][ni], af[mi], bfr[ni]);
    }
    if constexpr (CVTA) { if (t + 1 < nk) WRITEA(cur ^ 1); }
    asm volatile("s_waitcnt vmcnt(0)" ::: "memory");
    __syncthreads();
  }
#pragma unroll
  for (int mi = 0; mi < 4; ++mi)
    mfma_fence4(acc[mi][0], acc[mi][NI - 1], acc[mi][0], acc[mi][NI - 1]);
  if (g.vt[z]) {
    // output element (r, c) -> VT[(r>>11)*1024 + c][r & 2047], T=2048 (bf16)
    u16* VTo = (u16*)g.C[z];
    const int bbv = row0 >> 11;
#pragma unroll
    for (int mi = 0; mi < 4; ++mi) {
      const int r = row0 + wm * 64 + mi * 16 + l4 * 4;
      const int t0 = r & 2047;
#pragma unroll
      for (int ni = 0; ni < NI; ++ni) {
        const int c = col0 + wn * WNW + ni * 16 + l15;
        ushort4 ov = {f2bf(acc[mi][ni][0] * osc), f2bf(acc[mi][ni][1] * osc),
                      f2bf(acc[mi][ni][2] * osc), f2bf(acc[mi][ni][3] * osc)};
        *(ushort4*)(VTo + ((size_t)(bbv * 1024 + c)) * 2048 + t0) = ov;
      }
    }
  } else {
    OutT* __restrict__ C = (OutT*)g.C[z];
#pragma unroll
    for (int mi = 0; mi < 4; ++mi) {
      const int r = row0 + wm * 64 + mi * 16 + l4 * 4;
#pragma unroll
      for (int ni = 0; ni < NI; ++ni) {
        const int c = col0 + wn * WNW + ni * 16 + l15;
#pragma unroll
        for (int j = 0; j < 4; ++j) {
          float v = acc[mi][ni][j] * osc;
          if constexpr (sizeof(OutT) == 2)
            ((u16*)C)[(size_t)(r + j) * N + c] = f2bf(v);
          else
            ((float*)C)[(size_t)(r + j) * N + c] = v;
        }
      }
    }
  }
}

// ---------------- causal flash attention (swapped-QK, 4 waves x 32 q) -------
// Round-14 attn with ONE structural change (T3/T4 minimal): 3-buffer K/V
// rotation + COUNTED vmcnt + RAW s_barrier. __syncthreads() lowers to
// "s_waitcnt vmcnt(0) lgkmcnt(0); s_barrier" which fully drains the 4
// just-issued global_load_lds every iter (~450-900cy, the measured ~37%
// stall). New schedule per iter t: s_waitcnt vmcnt(4) (own tile-t loads
// retired; tile-t+1's 4 stay in flight) -> raw s_barrier (every wave waited
// its OWN tile-t loads, so post-barrier the union is visible) ->
// STAGE(t+2, (t+2)%3) (WAR-safe: buf[(t+2)%3]=buf[(t-1)%3]'s readers
// finished before this barrier) -> compute tile t. Loads get ~2 iters to
// land. LDS 48KB -> 3 blocks/CU (occupancy counter will DROP; dur is the
// verdict).
__global__ __launch_bounds__(256, 3) void attn_kernel(const u16* __restrict__ Qg,
                                                      const u16* __restrict__ Kg,
                                                      const u16* __restrict__ VTg,
                                                      u16* __restrict__ Yg) {
  __shared__ __align__(16) u16 Kt[3][64 * 64];
  __shared__ __align__(16) u16 Vt[3][64 * 64];
  const int tid = threadIdx.x;
  const int lane = tid & 63, w = tid >> 6;
  const int l31 = lane & 31, hi = lane >> 5;
  const int f = blockIdx.x;
  const int s = f >> 6;
  const int qt = (s < 4) ? 15 - 2 * s : (s < 8) ? 2 * s - 8
               : (s < 12) ? 30 - 2 * s : 2 * s - 23;
  const int bhid = f & 63;
  const int bb = bhid >> 4, h = bhid & 15;
  const size_t rb = (size_t)bb * 2048;
  const int h64 = h * 64;
  const int qb0 = qt << 7;             // 128-row q tile
  const int qg = qb0 + w * 32 + l31;   // this lane's q row
  const int qend = qb0 + w * 32 + 31;  // wave's last q row
  const u16* Kbh = Kg + rb * 1024 + h64;
  const u16* VTbh = VTg + (size_t)bhid * 64 * 2048;  // [64 d][2048 t]
  const int srow = lane >> 3;
  const int schunk = ((lane & 7) ^ srow) * 8;

  // Q frags (B-operand): elem e of qf[kd] = Q[qg][kd*16 + 8*hi + e]
  bf16x8 qf[4];
#pragma unroll
  for (int kd = 0; kd < 4; ++kd)
    qf[kd] = *(const bf16x8*)(Qg + (rb + qg) * 1024 + h64 + kd * 16 + 8 * hi);

  f32x16 o0 = {}, o1 = {};               // o^T: d rows (+0/+32), q = l31
  const float MNEG = -30000.f;           // bounded sentinel; exp2 -> 0
  float lrun = 0.f;

  auto STAGE = [&](int it, int buf) {    // 4 gloads per wave (2 K + 2 V)
    const int kv0 = it << 6;
    const int r0 = w * 16;
#pragma unroll
    for (int i = 0; i < 2; ++i) {
      gload_lds16(Kbh + (size_t)(kv0 + r0 + i * 8 + srow) * 1024 + schunk,
                  &Kt[buf][(r0 + i * 8) * 64]);
      gload_lds16(VTbh + (size_t)(r0 + i * 8 + srow) * 2048 + kv0 + schunk,
                  &Vt[buf][(r0 + i * 8) * 64]);
    }
  };
  STAGE(0, 0);
  STAGE(1, 1);

  const int nkv = 2 * qt + 2;            // >= 2 always
  for (int t = 0; t < nkv; ++t) {
    const int bufc = t % 3;
    // own tile-t loads retired (4 newer = tile t+1 may stay in flight)
    if (t + 1 < nkv) asm volatile("s_waitcnt vmcnt(4)" ::: "memory");
    else             asm volatile("s_waitcnt vmcnt(0)" ::: "memory");
    __builtin_amdgcn_s_barrier();
    asm volatile("" ::: "memory");
    // prefetch 2 ahead (WAR-safe post-barrier)
    if (t + 2 < nkv) STAGE(t + 2, (t + 2) % 3);
    const int kv0 = t << 6;
    if (kv0 <= qend) {
      // ---- QK^T (s in log2 domain; Q pre-scaled by 0.125*log2e)
      f32x16 s0 = {}, s1 = {};
      __builtin_amdgcn_s_setprio(1);
#pragma unroll
      for (int kd = 0; kd < 4; ++kd) {
        const int col = (kd * 16 + 8 * hi) ^ ((l31 & 7) << 3);
        bf16x8 kf0 = *(const bf16x8*)&Kt[bufc][l31 * 64 + col];
        bf16x8 kf1 = *(const bf16x8*)&Kt[bufc][(32 + l31) * 64 + col];
        mfma32(s0, kf0, qf[kd]);
        mfma32(s1, kf1, qf[kd]);
      }
      __builtin_amdgcn_s_setprio(0);
      fence16x2(s0, s1);
      // ---- causal mask (diag-band iters only; bounded sentinel)
      if (kv0 + 63 > qb0 + w * 32) {
        const int lim = qg - (kv0 + 4 * hi);
#pragma unroll
        for (int r = 0; r < 16; ++r) {
          const int C0 = (r & 3) + 8 * (r >> 2);
          if (C0 > lim) s0[r] = MNEG;
          if (C0 + 32 > lim) s1[r] = MNEG;
        }
      }
      // ---- p = exp2(s) via raw v_exp_f32
#pragma unroll
      for (int r = 0; r < 16; ++r) {
        s0[r] = __builtin_amdgcn_exp2f(s0[r]);
        s1[r] = __builtin_amdgcn_exp2f(s1[r]);
      }
      // ---- row sum (explicit tree) + cross-half
      float t8[8];
#pragma unroll
      for (int r = 0; r < 8; ++r)
        t8[r] = (s0[2 * r] + s0[2 * r + 1]) + (s1[2 * r] + s1[2 * r + 1]);
      float rs = ((t8[0] + t8[1]) + (t8[2] + t8[3])) +
                 ((t8[4] + t8[5]) + (t8[6] + t8[7]));
      lrun += rs + __shfl_xor(rs, 32, 64);
      // ---- pack P into B-frags via permlane32_swap (HW-verified order)
      i32x4 paw[4];
#pragma unroll
      for (int tl = 0; tl < 2; ++tl) {
        const f32x16& p = tl ? s1 : s0;
#pragma unroll
        for (int ks = 0; ks < 2; ++ks) {
          unsigned pk0 = cvtpk(p[8 * ks + 0], p[8 * ks + 1]);
          unsigned pk1 = cvtpk(p[8 * ks + 2], p[8 * ks + 3]);
          unsigned pk2 = cvtpk(p[8 * ks + 4], p[8 * ks + 5]);
          unsigned pk3 = cvtpk(p[8 * ks + 6], p[8 * ks + 7]);
          asm("v_permlane32_swap_b32 %0, %1" : "+v"(pk0), "+v"(pk2));
          asm("v_permlane32_swap_b32 %0, %1" : "+v"(pk1), "+v"(pk3));
          i32x4 A;
          A[0] = (int)pk0;
          A[1] = (int)pk1;
          A[2] = (int)pk2;
          A[3] = (int)pk3;
          paw[tl * 2 + ks] = A;
        }
      }
      asm volatile("s_nop 1");
      // ---- PV: o^T += V^T-frag x P-frag
      __builtin_amdgcn_s_setprio(1);
#pragma unroll
      for (int tl = 0; tl < 2; ++tl)
#pragma unroll
        for (int ks = 0; ks < 2; ++ks) {
          bf16x8 pa = __builtin_bit_cast(bf16x8, paw[tl * 2 + ks]);
          const int kvc = tl * 32 + ks * 16 + 8 * hi;
#pragma unroll
          for (int dt = 0; dt < 2; ++dt) {
            const int row = dt * 32 + l31;
            bf16x8 vf = *(const bf16x8*)&Vt[bufc][row * 64 + (kvc ^ ((l31 & 7) << 3))];
            if (dt == 0) mfma32(o0, vf, pa);
            else         mfma32(o1, vf, pa);
          }
        }
      __builtin_amdgcn_s_setprio(0);
    }
  }
  fence16x2(o0, o1);
  const float inv = 1.f / lrun;
  u16* Yrow = Yg + (rb + qg) * 1024 + h64;
#pragma unroll
  for (int r = 0; r < 16; r += 2) {
    const int dbase = (r & 3) + 8 * (r >> 2) + 4 * hi;
    *(unsigned*)(Yrow + dbase) = cvtpk(o0[r] * inv, o0[r + 1] * inv);
    *(unsigned*)(Yrow + 32 + dbase) = cvtpk(o1[r] * inv, o1[r + 1] * inv);
  }
}

// ---------------- launch ----------------
extern "C" void kernel_launch(void* const* d_in, const int* in_sizes, int n_in,
                              void* d_out, int out_size, void* d_ws, size_t ws_size,
                              hipStream_t stream) {
  const float* x = (const float*)d_in[0];
  char* ws = (char*)d_ws;
  u16* xb = (u16*)ws;                          // attention Y (bf16)
  u16* wb = (u16*)(ws + (16u << 20));          // 8 x 131072 bf16 weights
  u16* Rq = (u16*)(ws + (18u << 20));          // [8192][128]
  u16* Rk = (u16*)(ws + (20u << 20));
  u16* Rv = (u16*)(ws + (22u << 20));
  u16* Ry = (u16*)(ws + (24u << 20));
  u16* Qb = (u16*)(ws + (26u << 20));          // [8192][1024]
  u16* Kb = (u16*)(ws + (42u << 20));
  u16* VT = (u16*)(ws + (58u << 20));          // [64 bh][64 d][2048 t]
  const int WSZ = 131072;
  const float SC = 0.18033688011112042f;       // 0.125 * log2(e)

  W8 wp;
  for (int i = 0; i < 8; ++i) wp.s[i] = (const float*)d_in[1 + i];
  cvt_w_kernel<<<1024, 256, 0, stream>>>(wp, wb);

  // R_{q,k,v} = x @ {q,k,v}A^T (M=8192, N=128, K=1024), fp32 x converted
  // in-staging (CVTA), BM=64 -> 384 blocks
  G3 g1;
  g1.A[0] = g1.A[1] = g1.A[2] = (const u16*)x;
  g1.B[0] = wb; g1.B[1] = wb + 2 * WSZ; g1.B[2] = wb + 4 * WSZ;
  g1.C[0] = Rq; g1.C[1] = Rk; g1.C[2] = Rv;
  g1.osc[0] = g1.osc[1] = g1.osc[2] = 1.f;
  g1.vt[0] = g1.vt[1] = g1.vt[2] = 0;
  gemm_nt<u16, 64, true><<<dim3(128, 1, 3), 256, 0, stream>>>(g1, 8192, 128, 1024);

  // Q,K,V^T in ONE launch: Q scaled by SC; z=2 writes transposed V
  G3 g2;
  g2.A[0] = Rq; g2.A[1] = Rk; g2.A[2] = Rv;
  g2.B[0] = wb + 1 * WSZ; g2.B[1] = wb + 3 * WSZ; g2.B[2] = wb + 5 * WSZ;
  g2.C[0] = Qb; g2.C[1] = Kb; g2.C[2] = VT;
  g2.osc[0] = SC; g2.osc[1] = 1.f; g2.osc[2] = 1.f;
  g2.vt[0] = 0; g2.vt[1] = 0; g2.vt[2] = 1;
  gemm_nt<u16, 128, false><<<dim3(64, 8, 3), 256, 0, stream>>>(g2, 8192, 1024, 128);

  // Y (into xb) = causal attention
  attn_kernel<<<dim3(1024), 256, 0, stream>>>(Qb, Kb, VT, xb);

  // Ry = Y @ cA^T (BM=64 -> 128 blocks), out = Ry @ cB^T (fp32)
  G3 g3;
  g3.A[0] = g3.A[1] = g3.A[2] = xb;
  g3.B[0] = g3.B[1] = g3.B[2] = wb + 6 * WSZ;
  g3.C[0] = g3.C[1] = g3.C[2] = Ry;
  g3.osc[0] = g3.osc[1] = g3.osc[2] = 1.f;
  g3.vt[0] = g3.vt[1] = g3.vt[2] = 0;
  gemm_nt<u16, 64, false><<<dim3(128, 1, 1), 256, 0, stream>>>(g3, 8192, 128, 1024);
  G3 g4;
  g4.A[0] = g4.A[1] = g4.A[2] = Ry;
  g4.B[0] = g4.B[1] = g4.B[2] = wb + 7 * WSZ;
  g4.C[0] = g4.C[1] = g4.C[2] = d_out;
  g4.osc[0] = g4.osc[1] = g4.osc[2] = 1.f;
  g4.vt[0] = g4.vt[1] = g4.vt[2] = 0;
  gemm_nt<float, 128, false><<<dim3(64, 8, 1), 256, 0, stream>>>(g4, 8192, 1024, 128);
}

// Round 16
// 122.904 us; speedup vs baseline: 1.0410x; 1.0410x over previous
//
#include <hip/hip_runtime.h>

typedef unsigned short u16;
typedef __attribute__((ext_vector_type(8))) short bf16x8;   // 8 bf16 in 4 VGPRs
typedef __attribute__((ext_vector_type(4))) float f32x4;
typedef __attribute__((ext_vector_type(16))) float f32x16;
typedef __attribute__((ext_vector_type(4))) int i32x4;

typedef const __attribute__((address_space(1))) void gvoid_t;
typedef __attribute__((address_space(3))) void svoid_t;

// fp32 -> bf16 round-to-nearest-even
__device__ __forceinline__ u16 f2bf(float f) {
  unsigned u = __builtin_bit_cast(unsigned, f);
  u += 0x7fffu + ((u >> 16) & 1u);
  return (u16)(u >> 16);
}

// packed f32 pair -> 2xbf16 in one u32 (lo=a, hi=b)
__device__ __forceinline__ unsigned cvtpk(float a, float b) {
  unsigned r;
  asm("v_cvt_pk_bf16_f32 %0, %1, %2" : "=v"(r) : "v"(a), "v"(b));
  return r;
}

// async global->LDS, 16B per lane; lds base wave-uniform (HW adds lane*16)
__device__ __forceinline__ void gload_lds16(const u16* g, u16* ldsbase) {
  __builtin_amdgcn_global_load_lds((gvoid_t*)g, (svoid_t*)ldsbase, 16, 0, 0);
}

__device__ __forceinline__ void mfma16(f32x4& d, bf16x8 a, bf16x8 b) {
  asm("v_mfma_f32_16x16x32_bf16 %0, %1, %2, %0" : "+v"(d) : "v"(a), "v"(b));
}
__device__ __forceinline__ void mfma32(f32x16& d, bf16x8 a, bf16x8 b) {
  asm("v_mfma_f32_32x32x16_bf16 %0, %1, %2, %0" : "+v"(d) : "v"(a), "v"(b));
}
__device__ __forceinline__ void mfma_fence4(f32x4& a, f32x4& b, f32x4& c, f32x4& d) {
  asm volatile("s_nop 7\n\ts_nop 7" : "+v"(a), "+v"(b), "+v"(c), "+v"(d));
}
__device__ __forceinline__ void fence16x2(f32x16& a, f32x16& b) {
  asm volatile("s_nop 7\n\ts_nop 7\n\ts_nop 7" : "+v"(a), "+v"(b));
}

// ---------------- conversions (weights only; x handled inside g1) -----------
struct W8 { const float* s[8]; };
__global__ __launch_bounds__(256) void cvt_w_kernel(W8 w, u16* __restrict__ wb) {
  const int b = blockIdx.x;
  const int wi = b >> 7;
  const int wo = b & 127;
  const float* src = w.s[wi];
  u16* dst = wb + (size_t)wi * 131072;
  int i = (wo * 256 + (int)threadIdx.x) * 4;
  float4 v = *(const float4*)(src + i);
  ushort4 o = {f2bf(v.x), f2bf(v.y), f2bf(v.z), f2bf(v.w)};
  *(ushort4*)(dst + i) = o;
}

// ---------------- NT GEMM: C[m][n] = sum_k A[m][k] * B[n][k] ----------------
// BM x 128 tile, BK=64, 4 waves, double-buffered XOR-swizzled LDS.
// BM=128: waves 2x2 (each 64x64, 4x4 frags). BM=64: waves 1x4 (each 64x32,
// 4x2 frags). osc[z]: output scale. vt[z]: transposed bf16 output into
// [b*16+h][d][t=2048]. CVTA (BM=64): A is fp32, reg-staged cvt_pk ds_write.
// XCDMAP (g1): linear 384-block grid, bid -> (xcd=bid&7, slot=bid>>3,
// z=slot%3, rowtile=xcd*16+slot/3): the 3 z-blocks sharing a row-tile land
// on the SAME XCD in adjacent dispatch rounds -> x tile is an L2 hit for 2
// of 3 reads (x read 100.6MB -> ~35MB). Bijective -> correctness-neutral.
struct G3 { const u16* A[3]; const u16* B[3]; void* C[3]; float osc[3]; int vt[3]; };

template <typename OutT, int BM, bool CVTA, bool XCDMAP>
__global__ __launch_bounds__(256) void gemm_nt(G3 g, int M, int N, int K) {
  constexpr int NI = (BM == 128) ? 4 : 2;   // n-frags per wave
  __shared__ __align__(16) u16 At[2][BM * 64];
  __shared__ __align__(16) u16 Bt[2][128 * 64];
  int bx = blockIdx.x, by = blockIdx.y, bz = blockIdx.z;
  if constexpr (XCDMAP) {  // 384 linear blocks -> (rowtile, z), XCD-grouped
    const int xcd = bx & 7, slot = bx >> 3;
    bz = slot % 3;
    bx = xcd * 16 + slot / 3;
    by = 0;
  }
  const int z = bz;
  const u16* __restrict__ A = g.A[z];
  const float* __restrict__ Af = (const float*)g.A[z];
  const u16* __restrict__ Bw = g.B[z];
  const float osc = g.osc[z];
  const int tid = threadIdx.x;
  const int lane = tid & 63, w = tid >> 6;
  const int wm = (BM == 128) ? (w >> 1) : 0;
  const int wn = (BM == 128) ? (w & 1) : w;
  constexpr int WNW = (BM == 128) ? 64 : 32;  // wave n-width
  const int l15 = lane & 15, l4 = lane >> 4;
  const int row0 = bx * BM, col0 = by * 128;
  const int srow = lane >> 3;
  const int schunk = ((lane & 7) ^ srow) * 8;
  const u16* Ag = A + (size_t)(row0 + w * 8 + srow) * K + schunk;
  const u16* Bg = Bw + (size_t)(col0 + w * 8 + srow) * K + schunk;
  f32x4 acc[4][NI] = {};
  float4 ax[4];  // CVTA staging regs (BM=64: 2 instrs x 2 float4)
  auto STAGEB = [&](int k0, int buf) {
#pragma unroll
    for (int i = 0; i < 4; ++i)
      gload_lds16(Bg + (size_t)i * 32 * K + k0, &Bt[buf][(w * 8 + i * 32) * 64]);
  };
  auto STAGEA_G = [&](int k0, int buf) {
#pragma unroll
    for (int i = 0; i < BM / 32; ++i)
      gload_lds16(Ag + (size_t)i * 32 * K + k0, &At[buf][(w * 8 + i * 32) * 64]);
  };
  auto LOADA = [&](int k0) {  // CVTA: issue fp32 loads (held in regs)
#pragma unroll
    for (int i = 0; i < BM / 32; ++i) {
      const float* src = Af + (size_t)(row0 + w * 8 + i * 32 + srow) * K + k0 + schunk;
      ax[2 * i] = *(const float4*)src;
      ax[2 * i + 1] = *(const float4*)(src + 4);
    }
  };
  auto WRITEA = [&](int buf) {  // CVTA: cvt + ds_write (same layout as gload)
#pragma unroll
    for (int i = 0; i < BM / 32; ++i) {
      i32x4 d;
      d[0] = (int)cvtpk(ax[2 * i].x, ax[2 * i].y);
      d[1] = (int)cvtpk(ax[2 * i].z, ax[2 * i].w);
      d[2] = (int)cvtpk(ax[2 * i + 1].x, ax[2 * i + 1].y);
      d[3] = (int)cvtpk(ax[2 * i + 1].z, ax[2 * i + 1].w);
      *(i32x4*)&At[buf][(w * 8 + i * 32 + srow) * 64 + (lane & 7) * 8] = d;
    }
  };
  if constexpr (CVTA) LOADA(0); else STAGEA_G(0, 0);
  STAGEB(0, 0);
  if constexpr (CVTA) WRITEA(0);
  asm volatile("s_waitcnt vmcnt(0)" ::: "memory");
  __syncthreads();
  const int nk = K >> 6;
  for (int t = 0; t < nk; ++t) {
    const int cur = t & 1;
    if (t + 1 < nk) {
      if constexpr (CVTA) LOADA((t + 1) << 6); else STAGEA_G((t + 1) << 6, cur ^ 1);
      STAGEB((t + 1) << 6, cur ^ 1);
    }
#pragma unroll
    for (int kk = 0; kk < 64; kk += 32) {
      bf16x8 af[4], bfr[NI];
#pragma unroll
      for (int mi = 0; mi < 4; ++mi) {
        const int r = wm * 64 + mi * 16 + l15;
        af[mi] = *(const bf16x8*)&At[cur][r * 64 + ((kk + 8 * l4) ^ ((r & 7) << 3))];
      }
#pragma unroll
      for (int ni = 0; ni < NI; ++ni) {
        const int r = wn * WNW + ni * 16 + l15;
        bfr[ni] = *(const bf16x8*)&Bt[cur][r * 64 + ((kk + 8 * l4) ^ ((r & 7) << 3))];
      }
#pragma unroll
      for (int mi = 0; mi < 4; ++mi)
#pragma unroll
        for (int ni = 0; ni < NI; ++ni) mfma16(acc[mi][ni], af[mi], bfr[ni]);
    }
    if constexpr (CVTA) { if (t + 1 < nk) WRITEA(cur ^ 1); }
    asm volatile("s_waitcnt vmcnt(0)" ::: "memory");
    __syncthreads();
  }
#pragma unroll
  for (int mi = 0; mi < 4; ++mi)
    mfma_fence4(acc[mi][0], acc[mi][NI - 1], acc[mi][0], acc[mi][NI - 1]);
  if (g.vt[z]) {
    // output element (r, c) -> VT[(r>>11)*1024 + c][r & 2047], T=2048 (bf16)
    u16* VTo = (u16*)g.C[z];
    const int bbv = row0 >> 11;
#pragma unroll
    for (int mi = 0; mi < 4; ++mi) {
      const int r = row0 + wm * 64 + mi * 16 + l4 * 4;
      const int t0 = r & 2047;
#pragma unroll
      for (int ni = 0; ni < NI; ++ni) {
        const int c = col0 + wn * WNW + ni * 16 + l15;
        ushort4 ov = {f2bf(acc[mi][ni][0] * osc), f2bf(acc[mi][ni][1] * osc),
                      f2bf(acc[mi][ni][2] * osc), f2bf(acc[mi][ni][3] * osc)};
        *(ushort4*)(VTo + ((size_t)(bbv * 1024 + c)) * 2048 + t0) = ov;
      }
    }
  } else {
    OutT* __restrict__ C = (OutT*)g.C[z];
#pragma unroll
    for (int mi = 0; mi < 4; ++mi) {
      const int r = row0 + wm * 64 + mi * 16 + l4 * 4;
#pragma unroll
      for (int ni = 0; ni < NI; ++ni) {
        const int c = col0 + wn * WNW + ni * 16 + l15;
#pragma unroll
        for (int j = 0; j < 4; ++j) {
          float v = acc[mi][ni][j] * osc;
          if constexpr (sizeof(OutT) == 2)
            ((u16*)C)[(size_t)(r + j) * N + c] = f2bf(v);
          else
            ((float*)C)[(size_t)(r + j) * N + c] = v;
        }
      }
    }
  }
}

// ---------------- causal flash attention (swapped-QK, 4 waves x 32 q) -------
// ROUND-14 STRUCTURE EXACTLY (56.4us known-good): 1024 blocks, balanced qt
// map, 2-buffer LDS + __syncthreads, permlane32_swap pack (HW-verified
// order), exp2 builtin, unnormalized flash. r15's counted-vmcnt/3-buffer
// pipeline REVERTED: -1 block/CU occupancy cost exceeded the drain saving
// (58.4 vs 56.4) -> attn idle is latency-chain + occupancy, not drain.
__global__ __launch_bounds__(256, 4) void attn_kernel(const u16* __restrict__ Qg,
                                                      const u16* __restrict__ Kg,
                                                      const u16* __restrict__ VTg,
                                                      u16* __restrict__ Yg) {
  __shared__ __align__(16) u16 Kt[2][64 * 64];
  __shared__ __align__(16) u16 Vt[2][64 * 64];
  const int tid = threadIdx.x;
  const int lane = tid & 63, w = tid >> 6;
  const int l31 = lane & 31, hi = lane >> 5;
  const int f = blockIdx.x;
  const int s = f >> 6;
  const int qt = (s < 4) ? 15 - 2 * s : (s < 8) ? 2 * s - 8
               : (s < 12) ? 30 - 2 * s : 2 * s - 23;
  const int bhid = f & 63;
  const int bb = bhid >> 4, h = bhid & 15;
  const size_t rb = (size_t)bb * 2048;
  const int h64 = h * 64;
  const int qb0 = qt << 7;             // 128-row q tile
  const int qg = qb0 + w * 32 + l31;   // this lane's q row
  const int qend = qb0 + w * 32 + 31;  // wave's last q row
  const u16* Kbh = Kg + rb * 1024 + h64;
  const u16* VTbh = VTg + (size_t)bhid * 64 * 2048;  // [64 d][2048 t]
  const int srow = lane >> 3;
  const int schunk = ((lane & 7) ^ srow) * 8;

  // Q frags (B-operand): elem e of qf[kd] = Q[qg][kd*16 + 8*hi + e]
  bf16x8 qf[4];
#pragma unroll
  for (int kd = 0; kd < 4; ++kd)
    qf[kd] = *(const bf16x8*)(Qg + (rb + qg) * 1024 + h64 + kd * 16 + 8 * hi);

  f32x16 o0 = {}, o1 = {};               // o^T: d rows (+0/+32), q = l31
  const float MNEG = -30000.f;           // bounded sentinel; exp2 -> 0
  float lrun = 0.f;

  auto STAGE = [&](int it, int buf) {
    const int kv0 = it << 6;
    const int r0 = w * 16;
#pragma unroll
    for (int i = 0; i < 2; ++i) {
      gload_lds16(Kbh + (size_t)(kv0 + r0 + i * 8 + srow) * 1024 + schunk,
                  &Kt[buf][(r0 + i * 8) * 64]);
      gload_lds16(VTbh + (size_t)(r0 + i * 8 + srow) * 2048 + kv0 + schunk,
                  &Vt[buf][(r0 + i * 8) * 64]);
    }
  };
  STAGE(0, 0);
  asm volatile("s_waitcnt vmcnt(0)" ::: "memory");
  __syncthreads();

  const int nkv = 2 * qt + 2;
  for (int t = 0; t < nkv; ++t) {
    const int cur = t & 1;
    if (t + 1 < nkv) STAGE(t + 1, cur ^ 1);
    const int kv0 = t << 6;
    if (kv0 <= qend) {
      // ---- QK^T (s in log2 domain; Q pre-scaled by 0.125*log2e)
      f32x16 s0 = {}, s1 = {};
      __builtin_amdgcn_s_setprio(1);
#pragma unroll
      for (int kd = 0; kd < 4; ++kd) {
        const int col = (kd * 16 + 8 * hi) ^ ((l31 & 7) << 3);
        bf16x8 kf0 = *(const bf16x8*)&Kt[cur][l31 * 64 + col];
        bf16x8 kf1 = *(const bf16x8*)&Kt[cur][(32 + l31) * 64 + col];
        mfma32(s0, kf0, qf[kd]);
        mfma32(s1, kf1, qf[kd]);
      }
      __builtin_amdgcn_s_setprio(0);
      fence16x2(s0, s1);
      // ---- causal mask (diag-band iters only; bounded sentinel)
      if (kv0 + 63 > qb0 + w * 32) {
        const int lim = qg - (kv0 + 4 * hi);
#pragma unroll
        for (int r = 0; r < 16; ++r) {
          const int C0 = (r & 3) + 8 * (r >> 2);
          if (C0 > lim) s0[r] = MNEG;
          if (C0 + 32 > lim) s1[r] = MNEG;
        }
      }
      // ---- p = exp2(s) via raw v_exp_f32
#pragma unroll
      for (int r = 0; r < 16; ++r) {
        s0[r] = __builtin_amdgcn_exp2f(s0[r]);
        s1[r] = __builtin_amdgcn_exp2f(s1[r]);
      }
      // ---- row sum (explicit tree) + cross-half
      float t8[8];
#pragma unroll
      for (int r = 0; r < 8; ++r)
        t8[r] = (s0[2 * r] + s0[2 * r + 1]) + (s1[2 * r] + s1[2 * r + 1]);
      float rs = ((t8[0] + t8[1]) + (t8[2] + t8[3])) +
                 ((t8[4] + t8[5]) + (t8[6] + t8[7]));
      lrun += rs + __shfl_xor(rs, 32, 64);
      // ---- pack P into B-frags via permlane32_swap (HW-verified order)
      i32x4 paw[4];
#pragma unroll
      for (int tl = 0; tl < 2; ++tl) {
        const f32x16& p = tl ? s1 : s0;
#pragma unroll
        for (int ks = 0; ks < 2; ++ks) {
          unsigned pk0 = cvtpk(p[8 * ks + 0], p[8 * ks + 1]);
          unsigned pk1 = cvtpk(p[8 * ks + 2], p[8 * ks + 3]);
          unsigned pk2 = cvtpk(p[8 * ks + 4], p[8 * ks + 5]);
          unsigned pk3 = cvtpk(p[8 * ks + 6], p[8 * ks + 7]);
          asm("v_permlane32_swap_b32 %0, %1" : "+v"(pk0), "+v"(pk2));
          asm("v_permlane32_swap_b32 %0, %1" : "+v"(pk1), "+v"(pk3));
          i32x4 A;
          A[0] = (int)pk0;
          A[1] = (int)pk1;
          A[2] = (int)pk2;
          A[3] = (int)pk3;
          paw[tl * 2 + ks] = A;
        }
      }
      asm volatile("s_nop 1");
      // ---- PV: o^T += V^T-frag x P-frag
      __builtin_amdgcn_s_setprio(1);
#pragma unroll
      for (int tl = 0; tl < 2; ++tl)
#pragma unroll
        for (int ks = 0; ks < 2; ++ks) {
          bf16x8 pa = __builtin_bit_cast(bf16x8, paw[tl * 2 + ks]);
          const int kvc = tl * 32 + ks * 16 + 8 * hi;
#pragma unroll
          for (int dt = 0; dt < 2; ++dt) {
            const int row = dt * 32 + l31;
            bf16x8 vf = *(const bf16x8*)&Vt[cur][row * 64 + (kvc ^ ((l31 & 7) << 3))];
            if (dt == 0) mfma32(o0, vf, pa);
            else         mfma32(o1, vf, pa);
          }
        }
      __builtin_amdgcn_s_setprio(0);
    }
    asm volatile("s_waitcnt vmcnt(0)" ::: "memory");
    __syncthreads();
  }
  fence16x2(o0, o1);
  const float inv = 1.f / lrun;
  u16* Yrow = Yg + (rb + qg) * 1024 + h64;
#pragma unroll
  for (int r = 0; r < 16; r += 2) {
    const int dbase = (r & 3) + 8 * (r >> 2) + 4 * hi;
    *(unsigned*)(Yrow + dbase) = cvtpk(o0[r] * inv, o0[r + 1] * inv);
    *(unsigned*)(Yrow + 32 + dbase) = cvtpk(o1[r] * inv, o1[r + 1] * inv);
  }
}

// ---------------- launch ----------------
extern "C" void kernel_launch(void* const* d_in, const int* in_sizes, int n_in,
                              void* d_out, int out_size, void* d_ws, size_t ws_size,
                              hipStream_t stream) {
  const float* x = (const float*)d_in[0];
  char* ws = (char*)d_ws;
  u16* xb = (u16*)ws;                          // attention Y (bf16)
  u16* wb = (u16*)(ws + (16u << 20));          // 8 x 131072 bf16 weights
  u16* Rq = (u16*)(ws + (18u << 20));          // [8192][128]
  u16* Rk = (u16*)(ws + (20u << 20));
  u16* Rv = (u16*)(ws + (22u << 20));
  u16* Ry = (u16*)(ws + (24u << 20));
  u16* Qb = (u16*)(ws + (26u << 20));          // [8192][1024]
  u16* Kb = (u16*)(ws + (42u << 20));
  u16* VT = (u16*)(ws + (58u << 20));          // [64 bh][64 d][2048 t]
  const int WSZ = 131072;
  const float SC = 0.18033688011112042f;       // 0.125 * log2(e)

  W8 wp;
  for (int i = 0; i < 8; ++i) wp.s[i] = (const float*)d_in[1 + i];
  cvt_w_kernel<<<1024, 256, 0, stream>>>(wp, wb);

  // R_{q,k,v} = x @ {q,k,v}A^T (M=8192, N=128, K=1024), CVTA fp32-x,
  // XCD-grouped linear grid (384 blocks): 3 z-blocks per row-tile -> same XCD
  G3 g1;
  g1.A[0] = g1.A[1] = g1.A[2] = (const u16*)x;
  g1.B[0] = wb; g1.B[1] = wb + 2 * WSZ; g1.B[2] = wb + 4 * WSZ;
  g1.C[0] = Rq; g1.C[1] = Rk; g1.C[2] = Rv;
  g1.osc[0] = g1.osc[1] = g1.osc[2] = 1.f;
  g1.vt[0] = g1.vt[1] = g1.vt[2] = 0;
  gemm_nt<u16, 64, true, true><<<dim3(384), 256, 0, stream>>>(g1, 8192, 128, 1024);

  // Q,K,V^T in ONE launch: Q scaled by SC; z=2 writes transposed V
  G3 g2;
  g2.A[0] = Rq; g2.A[1] = Rk; g2.A[2] = Rv;
  g2.B[0] = wb + 1 * WSZ; g2.B[1] = wb + 3 * WSZ; g2.B[2] = wb + 5 * WSZ;
  g2.C[0] = Qb; g2.C[1] = Kb; g2.C[2] = VT;
  g2.osc[0] = SC; g2.osc[1] = 1.f; g2.osc[2] = 1.f;
  g2.vt[0] = 0; g2.vt[1] = 0; g2.vt[2] = 1;
  gemm_nt<u16, 128, false, false><<<dim3(64, 8, 3), 256, 0, stream>>>(g2, 8192, 1024, 128);

  // Y (into xb) = causal attention
  attn_kernel<<<dim3(1024), 256, 0, stream>>>(Qb, Kb, VT, xb);

  // Ry = Y @ cA^T (BM=64 -> 128 blocks), out = Ry @ cB^T (fp32)
  G3 g3;
  g3.A[0] = g3.A[1] = g3.A[2] = xb;
  g3.B[0] = g3.B[1] = g3.B[2] = wb + 6 * WSZ;
  g3.C[0] = g3.C[1] = g3.C[2] = Ry;
  g3.osc[0] = g3.osc[1] = g3.osc[2] = 1.f;
  g3.vt[0] = g3.vt[1] = g3.vt[2] = 0;
  gemm_nt<u16, 64, false, false><<<dim3(128, 1, 1), 256, 0, stream>>>(g3, 8192, 128, 1024);
  G3 g4;
  g4.A[0] = g4.A[1] = g4.A[2] = Ry;
  g4.B[0] = g4.B[1] = g4.B[2] = wb + 7 * WSZ;
  g4.C[0] = g4.C[1] = g4.C[2] = d_out;
  g4.osc[0] = g4.osc[1] = g4.osc[2] = 1.f;
  g4.vt[0] = g4.vt[1] = g4.vt[2] = 0;
  gemm_nt<float, 128, false, false><<<dim3(64, 8, 1), 256, 0, stream>>>(g4, 8192, 1024, 128);
}

// Round 17
// 120.602 us; speedup vs baseline: 1.0608x; 1.0191x over previous
//
#include <hip/hip_runtime.h>

typedef unsigned short u16;
typedef __attribute__((ext_vector_type(8))) short bf16x8;   // 8 bf16 in 4 VGPRs
typedef __attribute__((ext_vector_type(4))) float f32x4;
typedef __attribute__((ext_vector_type(16))) float f32x16;
typedef __attribute__((ext_vector_type(4))) int i32x4;

typedef const __attribute__((address_space(1))) void gvoid_t;
typedef __attribute__((address_space(3))) void svoid_t;

// fp32 -> bf16 round-to-nearest-even
__device__ __forceinline__ u16 f2bf(float f) {
  unsigned u = __builtin_bit_cast(unsigned, f);
  u += 0x7fffu + ((u >> 16) & 1u);
  return (u16)(u >> 16);
}

// packed f32 pair -> 2xbf16 in one u32 (lo=a, hi=b)
__device__ __forceinline__ unsigned cvtpk(float a, float b) {
  unsigned r;
  asm("v_cvt_pk_bf16_f32 %0, %1, %2" : "=v"(r) : "v"(a), "v"(b));
  return r;
}

// async global->LDS, 16B per lane; lds base wave-uniform (HW adds lane*16)
__device__ __forceinline__ void gload_lds16(const u16* g, u16* ldsbase) {
  __builtin_amdgcn_global_load_lds((gvoid_t*)g, (svoid_t*)ldsbase, 16, 0, 0);
}

__device__ __forceinline__ void mfma16(f32x4& d, bf16x8 a, bf16x8 b) {
  asm("v_mfma_f32_16x16x32_bf16 %0, %1, %2, %0" : "+v"(d) : "v"(a), "v"(b));
}
__device__ __forceinline__ void mfma32(f32x16& d, bf16x8 a, bf16x8 b) {
  asm("v_mfma_f32_32x32x16_bf16 %0, %1, %2, %0" : "+v"(d) : "v"(a), "v"(b));
}
__device__ __forceinline__ void mfma_fence2(f32x4& a, f32x4& b) {
  asm volatile("s_nop 7\n\ts_nop 7" : "+v"(a), "+v"(b));
}
__device__ __forceinline__ void fence16x2(f32x16& a, f32x16& b) {
  asm volatile("s_nop 7\n\ts_nop 7\n\ts_nop 7" : "+v"(a), "+v"(b));
}

// ---------------- conversions (weights only; x handled inside g1) -----------
struct W8 { const float* s[8]; };
__global__ __launch_bounds__(256) void cvt_w_kernel(W8 w, u16* __restrict__ wb) {
  const int b = blockIdx.x;
  const int wi = b >> 7;
  const int wo = b & 127;
  const float* src = w.s[wi];
  u16* dst = wb + (size_t)wi * 131072;
  int i = (wo * 256 + (int)threadIdx.x) * 4;
  float4 v = *(const float4*)(src + i);
  ushort4 o = {f2bf(v.x), f2bf(v.y), f2bf(v.z), f2bf(v.w)};
  *(ushort4*)(dst + i) = o;
}

// ---------------- NT GEMM: C[m][n] = sum_k A[m][k] * B[n][k] ----------------
// BM x 128 tile, BK=64, 4 waves, double-buffered XOR-swizzled LDS.
// BM=128: waves 2x2 (4x4 frags). BM=64: 1x4 (4x2). BM=32: 1x4 (2x2).
// osc[z]: output scale. vt[z]: transposed bf16 output [b*16+h][d][t=2048].
// CVTMODE: 0 = bf16 A via gload_lds; 1 = fp32 A reg-staged cvt_pk ds_write;
// 2 = TWO fp32 A arrays (A,A2) summed then cvt (split-K partial merge).
// koff[z]/klen: K-window (split-K); K param = row stride.
// XCDMAP: linear grid, bid -> (xcd=bid&7, slot=bid>>3, z=slot%3,
// rowtile=xcd*rpx+slot/3) so the 3 z-blocks sharing a row-tile land on one
// XCD in adjacent rounds (x L2-shared). Bijective.
struct G3 {
  const u16* A[3]; const float* A2[3]; const u16* B[3]; void* C[3];
  float osc[3]; int vt[3]; int koff[3]; int klen;
};

template <typename OutT, int BM, int CVTMODE, bool XCDMAP>
__global__ __launch_bounds__(256) void gemm_nt(G3 g, int M, int N, int K) {
  constexpr int MI = (BM == 32) ? 2 : 4;      // m-frags per wave
  constexpr int NI = (BM == 128) ? 4 : 2;     // n-frags per wave
  __shared__ __align__(16) u16 At[2][BM * 64];
  __shared__ __align__(16) u16 Bt[2][128 * 64];
  int bx = blockIdx.x, by = blockIdx.y, bz = blockIdx.z;
  if constexpr (XCDMAP) {
    const int rpx = (M / BM) >> 3;
    const int xcd = bx & 7, slot = bx >> 3;
    bz = slot % 3;
    bx = xcd * rpx + slot / 3;
    by = 0;
  }
  const int z = bz;
  const u16* __restrict__ A = g.A[z];
  const float* __restrict__ Af = (const float*)g.A[z];
  const float* __restrict__ Af2 = g.A2[z];
  const u16* __restrict__ Bw = g.B[z];
  const float osc = g.osc[z];
  const int koff = g.koff[z];
  const int tid = threadIdx.x;
  const int lane = tid & 63, w = tid >> 6;
  const int wm = (BM == 128) ? (w >> 1) : 0;
  const int wn = (BM == 128) ? (w & 1) : w;
  constexpr int WNW = (BM == 128) ? 64 : 32;  // wave n-width
  const int l15 = lane & 15, l4 = lane >> 4;
  const int row0 = bx * BM, col0 = by * 128;
  const int srow = lane >> 3;
  const int schunk = ((lane & 7) ^ srow) * 8;
  const u16* Ag = A + (size_t)(row0 + w * 8 + srow) * K + schunk;
  const u16* Bg = Bw + (size_t)(col0 + w * 8 + srow) * K + schunk;
  f32x4 acc[MI][NI] = {};
  float4 ax[2 * (BM / 32)], ax2[CVTMODE == 2 ? 2 * (BM / 32) : 1];
  auto STAGEB = [&](int k0, int buf) {
#pragma unroll
    for (int i = 0; i < 4; ++i)
      gload_lds16(Bg + (size_t)i * 32 * K + k0, &Bt[buf][(w * 8 + i * 32) * 64]);
  };
  auto STAGEA_G = [&](int k0, int buf) {
#pragma unroll
    for (int i = 0; i < BM / 32; ++i)
      gload_lds16(Ag + (size_t)i * 32 * K + k0, &At[buf][(w * 8 + i * 32) * 64]);
  };
  auto LOADA = [&](int k0) {  // CVTMODE>=1: issue fp32 loads (held in regs)
#pragma unroll
    for (int i = 0; i < BM / 32; ++i) {
      const size_t off = (size_t)(row0 + w * 8 + i * 32 + srow) * K + k0 + schunk;
      ax[2 * i] = *(const float4*)(Af + off);
      ax[2 * i + 1] = *(const float4*)(Af + off + 4);
      if constexpr (CVTMODE == 2) {
        ax2[2 * i] = *(const float4*)(Af2 + off);
        ax2[2 * i + 1] = *(const float4*)(Af2 + off + 4);
      }
    }
  };
  auto WRITEA = [&](int buf) {  // cvt(+sum) + ds_write (same layout as gload)
#pragma unroll
    for (int i = 0; i < BM / 32; ++i) {
      float4 a0 = ax[2 * i], a1 = ax[2 * i + 1];
      if constexpr (CVTMODE == 2) {
        const float4 b0 = ax2[2 * i], b1 = ax2[2 * i + 1];
        a0.x += b0.x; a0.y += b0.y; a0.z += b0.z; a0.w += b0.w;
        a1.x += b1.x; a1.y += b1.y; a1.z += b1.z; a1.w += b1.w;
      }
      i32x4 d;
      d[0] = (int)cvtpk(a0.x, a0.y);
      d[1] = (int)cvtpk(a0.z, a0.w);
      d[2] = (int)cvtpk(a1.x, a1.y);
      d[3] = (int)cvtpk(a1.z, a1.w);
      *(i32x4*)&At[buf][(w * 8 + i * 32 + srow) * 64 + (lane & 7) * 8] = d;
    }
  };
  if constexpr (CVTMODE) LOADA(koff); else STAGEA_G(koff, 0);
  STAGEB(koff, 0);
  if constexpr (CVTMODE) WRITEA(0);
  asm volatile("s_waitcnt vmcnt(0)" ::: "memory");
  __syncthreads();
  const int nk = g.klen >> 6;
  for (int t = 0; t < nk; ++t) {
    const int cur = t & 1;
    if (t + 1 < nk) {
      const int k1 = koff + ((t + 1) << 6);
      if constexpr (CVTMODE) LOADA(k1); else STAGEA_G(k1, cur ^ 1);
      STAGEB(k1, cur ^ 1);
    }
#pragma unroll
    for (int kk = 0; kk < 64; kk += 32) {
      bf16x8 af[MI], bfr[NI];
#pragma unroll
      for (int mi = 0; mi < MI; ++mi) {
        const int r = wm * 64 + mi * 16 + l15;
        af[mi] = *(const bf16x8*)&At[cur][r * 64 + ((kk + 8 * l4) ^ ((r & 7) << 3))];
      }
#pragma unroll
      for (int ni = 0; ni < NI; ++ni) {
        const int r = wn * WNW + ni * 16 + l15;
        bfr[ni] = *(const bf16x8*)&Bt[cur][r * 64 + ((kk + 8 * l4) ^ ((r & 7) << 3))];
      }
#pragma unroll
      for (int mi = 0; mi < MI; ++mi)
#pragma unroll
        for (int ni = 0; ni < NI; ++ni) mfma16(acc[mi][ni], af[mi], bfr[ni]);
    }
    if constexpr (CVTMODE != 0) { if (t + 1 < nk) WRITEA(cur ^ 1); }
    asm volatile("s_waitcnt vmcnt(0)" ::: "memory");
    __syncthreads();
  }
#pragma unroll
  for (int mi = 0; mi < MI; ++mi) mfma_fence2(acc[mi][0], acc[mi][NI - 1]);
  if (g.vt[z]) {
    // output element (r, c) -> VT[(r>>11)*1024 + c][r & 2047], T=2048 (bf16)
    u16* VTo = (u16*)g.C[z];
    const int bbv = row0 >> 11;
#pragma unroll
    for (int mi = 0; mi < MI; ++mi) {
      const int r = row0 + wm * 64 + mi * 16 + l4 * 4;
      const int t0 = r & 2047;
#pragma unroll
      for (int ni = 0; ni < NI; ++ni) {
        const int c = col0 + wn * WNW + ni * 16 + l15;
        ushort4 ov = {f2bf(acc[mi][ni][0] * osc), f2bf(acc[mi][ni][1] * osc),
                      f2bf(acc[mi][ni][2] * osc), f2bf(acc[mi][ni][3] * osc)};
        *(ushort4*)(VTo + ((size_t)(bbv * 1024 + c)) * 2048 + t0) = ov;
      }
    }
  } else {
    OutT* __restrict__ C = (OutT*)g.C[z];
#pragma unroll
    for (int mi = 0; mi < MI; ++mi) {
      const int r = row0 + wm * 64 + mi * 16 + l4 * 4;
#pragma unroll
      for (int ni = 0; ni < NI; ++ni) {
        const int c = col0 + wn * WNW + ni * 16 + l15;
#pragma unroll
        for (int j = 0; j < 4; ++j) {
          float v = acc[mi][ni][j] * osc;
          if constexpr (sizeof(OutT) == 2)
            ((u16*)C)[(size_t)(r + j) * N + c] = f2bf(v);
          else
            ((float*)C)[(size_t)(r + j) * N + c] = v;
        }
      }
    }
  }
}

// ---------------- causal flash attention (swapped-QK, 4 waves x 32 q) -------
// ROUND-14/16 STRUCTURE EXACTLY (56.3us known-good): 1024 blocks, balanced
// qt map, 2-buffer LDS + __syncthreads, permlane32_swap pack, exp2 builtin,
// unnormalized flash.
__global__ __launch_bounds__(256, 4) void attn_kernel(const u16* __restrict__ Qg,
                                                      const u16* __restrict__ Kg,
                                                      const u16* __restrict__ VTg,
                                                      u16* __restrict__ Yg) {
  __shared__ __align__(16) u16 Kt[2][64 * 64];
  __shared__ __align__(16) u16 Vt[2][64 * 64];
  const int tid = threadIdx.x;
  const int lane = tid & 63, w = tid >> 6;
  const int l31 = lane & 31, hi = lane >> 5;
  const int f = blockIdx.x;
  const int s = f >> 6;
  const int qt = (s < 4) ? 15 - 2 * s : (s < 8) ? 2 * s - 8
               : (s < 12) ? 30 - 2 * s : 2 * s - 23;
  const int bhid = f & 63;
  const int bb = bhid >> 4, h = bhid & 15;
  const size_t rb = (size_t)bb * 2048;
  const int h64 = h * 64;
  const int qb0 = qt << 7;             // 128-row q tile
  const int qg = qb0 + w * 32 + l31;   // this lane's q row
  const int qend = qb0 + w * 32 + 31;  // wave's last q row
  const u16* Kbh = Kg + rb * 1024 + h64;
  const u16* VTbh = VTg + (size_t)bhid * 64 * 2048;  // [64 d][2048 t]
  const int srow = lane >> 3;
  const int schunk = ((lane & 7) ^ srow) * 8;

  // Q frags (B-operand): elem e of qf[kd] = Q[qg][kd*16 + 8*hi + e]
  bf16x8 qf[4];
#pragma unroll
  for (int kd = 0; kd < 4; ++kd)
    qf[kd] = *(const bf16x8*)(Qg + (rb + qg) * 1024 + h64 + kd * 16 + 8 * hi);

  f32x16 o0 = {}, o1 = {};               // o^T: d rows (+0/+32), q = l31
  const float MNEG = -30000.f;           // bounded sentinel; exp2 -> 0
  float lrun = 0.f;

  auto STAGE = [&](int it, int buf) {
    const int kv0 = it << 6;
    const int r0 = w * 16;
#pragma unroll
    for (int i = 0; i < 2; ++i) {
      gload_lds16(Kbh + (size_t)(kv0 + r0 + i * 8 + srow) * 1024 + schunk,
                  &Kt[buf][(r0 + i * 8) * 64]);
      gload_lds16(VTbh + (size_t)(r0 + i * 8 + srow) * 2048 + kv0 + schunk,
                  &Vt[buf][(r0 + i * 8) * 64]);
    }
  };
  STAGE(0, 0);
  asm volatile("s_waitcnt vmcnt(0)" ::: "memory");
  __syncthreads();

  const int nkv = 2 * qt + 2;
  for (int t = 0; t < nkv; ++t) {
    const int cur = t & 1;
    if (t + 1 < nkv) STAGE(t + 1, cur ^ 1);
    const int kv0 = t << 6;
    if (kv0 <= qend) {
      // ---- QK^T (s in log2 domain; Q pre-scaled by 0.125*log2e)
      f32x16 s0 = {}, s1 = {};
      __builtin_amdgcn_s_setprio(1);
#pragma unroll
      for (int kd = 0; kd < 4; ++kd) {
        const int col = (kd * 16 + 8 * hi) ^ ((l31 & 7) << 3);
        bf16x8 kf0 = *(const bf16x8*)&Kt[cur][l31 * 64 + col];
        bf16x8 kf1 = *(const bf16x8*)&Kt[cur][(32 + l31) * 64 + col];
        mfma32(s0, kf0, qf[kd]);
        mfma32(s1, kf1, qf[kd]);
      }
      __builtin_amdgcn_s_setprio(0);
      fence16x2(s0, s1);
      // ---- causal mask (diag-band iters only; bounded sentinel)
      if (kv0 + 63 > qb0 + w * 32) {
        const int lim = qg - (kv0 + 4 * hi);
#pragma unroll
        for (int r = 0; r < 16; ++r) {
          const int C0 = (r & 3) + 8 * (r >> 2);
          if (C0 > lim) s0[r] = MNEG;
          if (C0 + 32 > lim) s1[r] = MNEG;
        }
      }
      // ---- p = exp2(s) via raw v_exp_f32
#pragma unroll
      for (int r = 0; r < 16; ++r) {
        s0[r] = __builtin_amdgcn_exp2f(s0[r]);
        s1[r] = __builtin_amdgcn_exp2f(s1[r]);
      }
      // ---- row sum (explicit tree) + cross-half
      float t8[8];
#pragma unroll
      for (int r = 0; r < 8; ++r)
        t8[r] = (s0[2 * r] + s0[2 * r + 1]) + (s1[2 * r] + s1[2 * r + 1]);
      float rs = ((t8[0] + t8[1]) + (t8[2] + t8[3])) +
                 ((t8[4] + t8[5]) + (t8[6] + t8[7]));
      lrun += rs + __shfl_xor(rs, 32, 64);
      // ---- pack P into B-frags via permlane32_swap (HW-verified order)
      i32x4 paw[4];
#pragma unroll
      for (int tl = 0; tl < 2; ++tl) {
        const f32x16& p = tl ? s1 : s0;
#pragma unroll
        for (int ks = 0; ks < 2; ++ks) {
          unsigned pk0 = cvtpk(p[8 * ks + 0], p[8 * ks + 1]);
          unsigned pk1 = cvtpk(p[8 * ks + 2], p[8 * ks + 3]);
          unsigned pk2 = cvtpk(p[8 * ks + 4], p[8 * ks + 5]);
          unsigned pk3 = cvtpk(p[8 * ks + 6], p[8 * ks + 7]);
          asm("v_permlane32_swap_b32 %0, %1" : "+v"(pk0), "+v"(pk2));
          asm("v_permlane32_swap_b32 %0, %1" : "+v"(pk1), "+v"(pk3));
          i32x4 A;
          A[0] = (int)pk0;
          A[1] = (int)pk1;
          A[2] = (int)pk2;
          A[3] = (int)pk3;
          paw[tl * 2 + ks] = A;
        }
      }
      asm volatile("s_nop 1");
      // ---- PV: o^T += V^T-frag x P-frag
      __builtin_amdgcn_s_setprio(1);
#pragma unroll
      for (int tl = 0; tl < 2; ++tl)
#pragma unroll
        for (int ks = 0; ks < 2; ++ks) {
          bf16x8 pa = __builtin_bit_cast(bf16x8, paw[tl * 2 + ks]);
          const int kvc = tl * 32 + ks * 16 + 8 * hi;
#pragma unroll
          for (int dt = 0; dt < 2; ++dt) {
            const int row = dt * 32 + l31;
            bf16x8 vf = *(const bf16x8*)&Vt[cur][row * 64 + (kvc ^ ((l31 & 7) << 3))];
            if (dt == 0) mfma32(o0, vf, pa);
            else         mfma32(o1, vf, pa);
          }
        }
      __builtin_amdgcn_s_setprio(0);
    }
    asm volatile("s_waitcnt vmcnt(0)" ::: "memory");
    __syncthreads();
  }
  fence16x2(o0, o1);
  const float inv = 1.f / lrun;
  u16* Yrow = Yg + (rb + qg) * 1024 + h64;
#pragma unroll
  for (int r = 0; r < 16; r += 2) {
    const int dbase = (r & 3) + 8 * (r >> 2) + 4 * hi;
    *(unsigned*)(Yrow + dbase) = cvtpk(o0[r] * inv, o0[r + 1] * inv);
    *(unsigned*)(Yrow + 32 + dbase) = cvtpk(o1[r] * inv, o1[r + 1] * inv);
  }
}

// ---------------- launch ----------------
extern "C" void kernel_launch(void* const* d_in, const int* in_sizes, int n_in,
                              void* d_out, int out_size, void* d_ws, size_t ws_size,
                              hipStream_t stream) {
  const float* x = (const float*)d_in[0];
  char* ws = (char*)d_ws;
  u16* xb = (u16*)ws;                          // attention Y (bf16)
  u16* wb = (u16*)(ws + (16u << 20));          // 8 x 131072 bf16 weights
  u16* Rq = (u16*)(ws + (18u << 20));          // [8192][128]
  u16* Rk = (u16*)(ws + (20u << 20));
  u16* Rv = (u16*)(ws + (22u << 20));
  u16* Qb = (u16*)(ws + (26u << 20));          // [8192][1024]
  u16* Kb = (u16*)(ws + (42u << 20));
  u16* VT = (u16*)(ws + (58u << 20));          // [64 bh][64 d][2048 t]
  float* Ry0 = (float*)(ws + (18u << 20));     // fp32 K-half partials (g3;
  float* Ry1 = (float*)(ws + (22u << 20));     //  Rq/Rk/Rv dead after attn)
  const int WSZ = 131072;
  const float SC = 0.18033688011112042f;       // 0.125 * log2(e)

  W8 wp;
  for (int i = 0; i < 8; ++i) wp.s[i] = (const float*)d_in[1 + i];
  cvt_w_kernel<<<1024, 256, 0, stream>>>(wp, wb);

  // R_{q,k,v} = x @ {q,k,v}A^T (M=8192, N=128, K=1024), CVTA fp32-x,
  // BM=32 + XCD-grouped linear grid: 768 blocks = 3/CU uniform, one round
  G3 g1 = {};
  g1.A[0] = g1.A[1] = g1.A[2] = (const u16*)x;
  g1.B[0] = wb; g1.B[1] = wb + 2 * WSZ; g1.B[2] = wb + 4 * WSZ;
  g1.C[0] = Rq; g1.C[1] = Rk; g1.C[2] = Rv;
  g1.osc[0] = g1.osc[1] = g1.osc[2] = 1.f;
  g1.klen = 1024;
  gemm_nt<u16, 32, 1, true><<<dim3(768), 256, 0, stream>>>(g1, 8192, 128, 1024);

  // Q,K,V^T in ONE launch: Q scaled by SC; z=2 writes transposed V
  G3 g2 = {};
  g2.A[0] = Rq; g2.A[1] = Rk; g2.A[2] = Rv;
  g2.B[0] = wb + 1 * WSZ; g2.B[1] = wb + 3 * WSZ; g2.B[2] = wb + 5 * WSZ;
  g2.C[0] = Qb; g2.C[1] = Kb; g2.C[2] = VT;
  g2.osc[0] = SC; g2.osc[1] = 1.f; g2.osc[2] = 1.f;
  g2.vt[2] = 1;
  g2.klen = 128;
  gemm_nt<u16, 128, 0, false><<<dim3(64, 8, 3), 256, 0, stream>>>(g2, 8192, 1024, 128);

  // Y (into xb) = causal attention
  attn_kernel<<<dim3(1024), 256, 0, stream>>>(Qb, Kb, VT, xb);

  // Ry = Y @ cA^T split-K (2 fp32 partials), BM=32 -> 512 blocks = 2/CU
  G3 g3 = {};
  g3.A[0] = g3.A[1] = xb;
  g3.B[0] = g3.B[1] = wb + 6 * WSZ;
  g3.C[0] = Ry0; g3.C[1] = Ry1;
  g3.osc[0] = g3.osc[1] = 1.f;
  g3.koff[0] = 0; g3.koff[1] = 512;
  g3.klen = 512;
  gemm_nt<float, 32, 0, false><<<dim3(256, 1, 2), 256, 0, stream>>>(g3, 8192, 128, 1024);

  // out = (Ry0+Ry1) @ cB^T (fp32): CVTMODE=2 sums partials in-staging;
  // BM=64 -> 1024 blocks = 4/CU
  G3 g4 = {};
  g4.A[0] = (const u16*)Ry0; g4.A2[0] = Ry1;
  g4.B[0] = wb + 7 * WSZ;
  g4.C[0] = d_out;
  g4.osc[0] = 1.f;
  g4.klen = 128;
  gemm_nt<float, 64, 2, false><<<dim3(128, 8, 1), 256, 0, stream>>>(g4, 8192, 1024, 128);
}

// Round 19
// 120.548 us; speedup vs baseline: 1.0613x; 1.0004x over previous
//
#include <hip/hip_runtime.h>

typedef unsigned short u16;
typedef __attribute__((ext_vector_type(8))) short bf16x8;   // 8 bf16 in 4 VGPRs
typedef __attribute__((ext_vector_type(4))) float f32x4;
typedef __attribute__((ext_vector_type(16))) float f32x16;
typedef __attribute__((ext_vector_type(4))) int i32x4;

typedef const __attribute__((address_space(1))) void gvoid_t;
typedef __attribute__((address_space(3))) void svoid_t;

// fp32 -> bf16 round-to-nearest-even
__device__ __forceinline__ u16 f2bf(float f) {
  unsigned u = __builtin_bit_cast(unsigned, f);
  u += 0x7fffu + ((u >> 16) & 1u);
  return (u16)(u >> 16);
}

// packed f32 pair -> 2xbf16 in one u32 (lo=a, hi=b)
__device__ __forceinline__ unsigned cvtpk(float a, float b) {
  unsigned r;
  asm("v_cvt_pk_bf16_f32 %0, %1, %2" : "=v"(r) : "v"(a), "v"(b));
  return r;
}

// async global->LDS, 16B per lane; lds base wave-uniform (HW adds lane*16)
__device__ __forceinline__ void gload_lds16(const u16* g, u16* ldsbase) {
  __builtin_amdgcn_global_load_lds((gvoid_t*)g, (svoid_t*)ldsbase, 16, 0, 0);
}

__device__ __forceinline__ void mfma16(f32x4& d, bf16x8 a, bf16x8 b) {
  asm("v_mfma_f32_16x16x32_bf16 %0, %1, %2, %0" : "+v"(d) : "v"(a), "v"(b));
}
__device__ __forceinline__ void mfma32(f32x16& d, bf16x8 a, bf16x8 b) {
  asm("v_mfma_f32_32x32x16_bf16 %0, %1, %2, %0" : "+v"(d) : "v"(a), "v"(b));
}
__device__ __forceinline__ void mfma_fence2(f32x4& a, f32x4& b) {
  asm volatile("s_nop 7\n\ts_nop 7" : "+v"(a), "+v"(b));
}
__device__ __forceinline__ void fence16x2(f32x16& a, f32x16& b) {
  asm volatile("s_nop 7\n\ts_nop 7\n\ts_nop 7" : "+v"(a), "+v"(b));
}

// ---------------- conversions (weights only; x handled inside g1) -----------
struct W8 { const float* s[8]; };
__global__ __launch_bounds__(256) void cvt_w_kernel(W8 w, u16* __restrict__ wb) {
  const int b = blockIdx.x;
  const int wi = b >> 7;
  const int wo = b & 127;
  const float* src = w.s[wi];
  u16* dst = wb + (size_t)wi * 131072;
  int i = (wo * 256 + (int)threadIdx.x) * 4;
  float4 v = *(const float4*)(src + i);
  ushort4 o = {f2bf(v.x), f2bf(v.y), f2bf(v.z), f2bf(v.w)};
  *(ushort4*)(dst + i) = o;
}

// ---------------- NT GEMM: C[m][n] = sum_k A[m][k] * B[n][k] ----------------
// BM x 128 tile, BK=64, 4 waves, double-buffered XOR-swizzled LDS.
// BM=128: waves 2x2 (4x4 frags). BM=64: 1x4 (4x2). BM=32: 1x4 (2x2).
// osc[z]: output scale. vt[z]: transposed bf16 output [b*16+h][d][t=2048].
// CVTMODE: 0 = bf16 A via gload_lds; 1 = fp32 A reg-staged cvt_pk ds_write;
// 2 = TWO fp32 A arrays (A,A2) summed then cvt (split-K partial merge).
// koff[z]/klen: K-window (split-K); K param = row stride.
// XCDMAP: linear grid, bid -> (xcd=bid&7, slot=bid>>3, z=slot%3,
// rowtile=xcd*rpx+slot/3) so the 3 z-blocks sharing a row-tile land on one
// XCD in adjacent rounds (x L2-shared). Bijective.
struct G3 {
  const u16* A[3]; const float* A2[3]; const u16* B[3]; void* C[3];
  float osc[3]; int vt[3]; int koff[3]; int klen;
};

template <typename OutT, int BM, int CVTMODE, bool XCDMAP>
__global__ __launch_bounds__(256) void gemm_nt(G3 g, int M, int N, int K) {
  constexpr int MI = (BM == 32) ? 2 : 4;      // m-frags per wave
  constexpr int NI = (BM == 128) ? 4 : 2;     // n-frags per wave
  __shared__ __align__(16) u16 At[2][BM * 64];
  __shared__ __align__(16) u16 Bt[2][128 * 64];
  int bx = blockIdx.x, by = blockIdx.y, bz = blockIdx.z;
  if constexpr (XCDMAP) {
    const int rpx = (M / BM) >> 3;
    const int xcd = bx & 7, slot = bx >> 3;
    bz = slot % 3;
    bx = xcd * rpx + slot / 3;
    by = 0;
  }
  const int z = bz;
  const u16* __restrict__ A = g.A[z];
  const float* __restrict__ Af = (const float*)g.A[z];
  const float* __restrict__ Af2 = g.A2[z];
  const u16* __restrict__ Bw = g.B[z];
  const float osc = g.osc[z];
  const int koff = g.koff[z];
  const int tid = threadIdx.x;
  const int lane = tid & 63, w = tid >> 6;
  const int wm = (BM == 128) ? (w >> 1) : 0;
  const int wn = (BM == 128) ? (w & 1) : w;
  constexpr int WNW = (BM == 128) ? 64 : 32;  // wave n-width
  const int l15 = lane & 15, l4 = lane >> 4;
  const int row0 = bx * BM, col0 = by * 128;
  const int srow = lane >> 3;
  const int schunk = ((lane & 7) ^ srow) * 8;
  const u16* Ag = A + (size_t)(row0 + w * 8 + srow) * K + schunk;
  const u16* Bg = Bw + (size_t)(col0 + w * 8 + srow) * K + schunk;
  f32x4 acc[MI][NI] = {};
  float4 ax[2 * (BM / 32)], ax2[CVTMODE == 2 ? 2 * (BM / 32) : 1];
  auto STAGEB = [&](int k0, int buf) {
#pragma unroll
    for (int i = 0; i < 4; ++i)
      gload_lds16(Bg + (size_t)i * 32 * K + k0, &Bt[buf][(w * 8 + i * 32) * 64]);
  };
  auto STAGEA_G = [&](int k0, int buf) {
#pragma unroll
    for (int i = 0; i < BM / 32; ++i)
      gload_lds16(Ag + (size_t)i * 32 * K + k0, &At[buf][(w * 8 + i * 32) * 64]);
  };
  auto LOADA = [&](int k0) {  // CVTMODE>=1: issue fp32 loads (held in regs)
#pragma unroll
    for (int i = 0; i < BM / 32; ++i) {
      const size_t off = (size_t)(row0 + w * 8 + i * 32 + srow) * K + k0 + schunk;
      ax[2 * i] = *(const float4*)(Af + off);
      ax[2 * i + 1] = *(const float4*)(Af + off + 4);
      if constexpr (CVTMODE == 2) {
        ax2[2 * i] = *(const float4*)(Af2 + off);
        ax2[2 * i + 1] = *(const float4*)(Af2 + off + 4);
      }
    }
  };
  auto WRITEA = [&](int buf) {  // cvt(+sum) + ds_write (same layout as gload)
#pragma unroll
    for (int i = 0; i < BM / 32; ++i) {
      float4 a0 = ax[2 * i], a1 = ax[2 * i + 1];
      if constexpr (CVTMODE == 2) {
        const float4 b0 = ax2[2 * i], b1 = ax2[2 * i + 1];
        a0.x += b0.x; a0.y += b0.y; a0.z += b0.z; a0.w += b0.w;
        a1.x += b1.x; a1.y += b1.y; a1.z += b1.z; a1.w += b1.w;
      }
      i32x4 d;
      d[0] = (int)cvtpk(a0.x, a0.y);
      d[1] = (int)cvtpk(a0.z, a0.w);
      d[2] = (int)cvtpk(a1.x, a1.y);
      d[3] = (int)cvtpk(a1.z, a1.w);
      *(i32x4*)&At[buf][(w * 8 + i * 32 + srow) * 64 + (lane & 7) * 8] = d;
    }
  };
  if constexpr (CVTMODE) LOADA(koff); else STAGEA_G(koff, 0);
  STAGEB(koff, 0);
  if constexpr (CVTMODE) WRITEA(0);
  asm volatile("s_waitcnt vmcnt(0)" ::: "memory");
  __syncthreads();
  const int nk = g.klen >> 6;
  for (int t = 0; t < nk; ++t) {
    const int cur = t & 1;
    if (t + 1 < nk) {
      const int k1 = koff + ((t + 1) << 6);
      if constexpr (CVTMODE) LOADA(k1); else STAGEA_G(k1, cur ^ 1);
      STAGEB(k1, cur ^ 1);
    }
#pragma unroll
    for (int kk = 0; kk < 64; kk += 32) {
      bf16x8 af[MI], bfr[NI];
#pragma unroll
      for (int mi = 0; mi < MI; ++mi) {
        const int r = wm * 64 + mi * 16 + l15;
        af[mi] = *(const bf16x8*)&At[cur][r * 64 + ((kk + 8 * l4) ^ ((r & 7) << 3))];
      }
#pragma unroll
      for (int ni = 0; ni < NI; ++ni) {
        const int r = wn * WNW + ni * 16 + l15;
        bfr[ni] = *(const bf16x8*)&Bt[cur][r * 64 + ((kk + 8 * l4) ^ ((r & 7) << 3))];
      }
#pragma unroll
      for (int mi = 0; mi < MI; ++mi)
#pragma unroll
        for (int ni = 0; ni < NI; ++ni) mfma16(acc[mi][ni], af[mi], bfr[ni]);
    }
    if constexpr (CVTMODE != 0) { if (t + 1 < nk) WRITEA(cur ^ 1); }
    asm volatile("s_waitcnt vmcnt(0)" ::: "memory");
    __syncthreads();
  }
#pragma unroll
  for (int mi = 0; mi < MI; ++mi) mfma_fence2(acc[mi][0], acc[mi][NI - 1]);
  if (g.vt[z]) {
    // output element (r, c) -> VT[(r>>11)*1024 + c][r & 2047], T=2048 (bf16)
    u16* VTo = (u16*)g.C[z];
    const int bbv = row0 >> 11;
#pragma unroll
    for (int mi = 0; mi < MI; ++mi) {
      const int r = row0 + wm * 64 + mi * 16 + l4 * 4;
      const int t0 = r & 2047;
#pragma unroll
      for (int ni = 0; ni < NI; ++ni) {
        const int c = col0 + wn * WNW + ni * 16 + l15;
        ushort4 ov = {f2bf(acc[mi][ni][0] * osc), f2bf(acc[mi][ni][1] * osc),
                      f2bf(acc[mi][ni][2] * osc), f2bf(acc[mi][ni][3] * osc)};
        *(ushort4*)(VTo + ((size_t)(bbv * 1024 + c)) * 2048 + t0) = ov;
      }
    }
  } else {
    OutT* __restrict__ C = (OutT*)g.C[z];
#pragma unroll
    for (int mi = 0; mi < MI; ++mi) {
      const int r = row0 + wm * 64 + mi * 16 + l4 * 4;
#pragma unroll
      for (int ni = 0; ni < NI; ++ni) {
        const int c = col0 + wn * WNW + ni * 16 + l15;
#pragma unroll
        for (int j = 0; j < 4; ++j) {
          float v = acc[mi][ni][j] * osc;
          if constexpr (sizeof(OutT) == 2)
            ((u16*)C)[(size_t)(r + j) * N + c] = f2bf(v);
          else
            ((float*)C)[(size_t)(r + j) * N + c] = v;
        }
      }
    }
  }
}

// ---------------- causal flash attention (swapped-QK, 4 waves x 32 q) -------
// ROUND-14/16/17 STRUCTURE EXACTLY (56.3us known-good): 1024 blocks, balanced
// qt map, 2-buffer LDS + __syncthreads, permlane32_swap pack (HW-verified
// order), exp2 builtin, unnormalized flash. Pipeline variants (r15 counted-
// vmcnt 3-buf: slower; r18 two-deep score pipeline: wrong) both REVERTED.
__global__ __launch_bounds__(256, 4) void attn_kernel(const u16* __restrict__ Qg,
                                                      const u16* __restrict__ Kg,
                                                      const u16* __restrict__ VTg,
                                                      u16* __restrict__ Yg) {
  __shared__ __align__(16) u16 Kt[2][64 * 64];
  __shared__ __align__(16) u16 Vt[2][64 * 64];
  const int tid = threadIdx.x;
  const int lane = tid & 63, w = tid >> 6;
  const int l31 = lane & 31, hi = lane >> 5;
  const int f = blockIdx.x;
  const int s = f >> 6;
  const int qt = (s < 4) ? 15 - 2 * s : (s < 8) ? 2 * s - 8
               : (s < 12) ? 30 - 2 * s : 2 * s - 23;
  const int bhid = f & 63;
  const int bb = bhid >> 4, h = bhid & 15;
  const size_t rb = (size_t)bb * 2048;
  const int h64 = h * 64;
  const int qb0 = qt << 7;             // 128-row q tile
  const int qg = qb0 + w * 32 + l31;   // this lane's q row
  const int qend = qb0 + w * 32 + 31;  // wave's last q row
  const u16* Kbh = Kg + rb * 1024 + h64;
  const u16* VTbh = VTg + (size_t)bhid * 64 * 2048;  // [64 d][2048 t]
  const int srow = lane >> 3;
  const int schunk = ((lane & 7) ^ srow) * 8;

  // Q frags (B-operand): elem e of qf[kd] = Q[qg][kd*16 + 8*hi + e]
  bf16x8 qf[4];
#pragma unroll
  for (int kd = 0; kd < 4; ++kd)
    qf[kd] = *(const bf16x8*)(Qg + (rb + qg) * 1024 + h64 + kd * 16 + 8 * hi);

  f32x16 o0 = {}, o1 = {};               // o^T: d rows (+0/+32), q = l31
  const float MNEG = -30000.f;           // bounded sentinel; exp2 -> 0
  float lrun = 0.f;

  auto STAGE = [&](int it, int buf) {
    const int kv0 = it << 6;
    const int r0 = w * 16;
#pragma unroll
    for (int i = 0; i < 2; ++i) {
      gload_lds16(Kbh + (size_t)(kv0 + r0 + i * 8 + srow) * 1024 + schunk,
                  &Kt[buf][(r0 + i * 8) * 64]);
      gload_lds16(VTbh + (size_t)(r0 + i * 8 + srow) * 2048 + kv0 + schunk,
                  &Vt[buf][(r0 + i * 8) * 64]);
    }
  };
  STAGE(0, 0);
  asm volatile("s_waitcnt vmcnt(0)" ::: "memory");
  __syncthreads();

  const int nkv = 2 * qt + 2;
  for (int t = 0; t < nkv; ++t) {
    const int cur = t & 1;
    if (t + 1 < nkv) STAGE(t + 1, cur ^ 1);
    const int kv0 = t << 6;
    if (kv0 <= qend) {
      // ---- QK^T (s in log2 domain; Q pre-scaled by 0.125*log2e)
      f32x16 s0 = {}, s1 = {};
      __builtin_amdgcn_s_setprio(1);
#pragma unroll
      for (int kd = 0; kd < 4; ++kd) {
        const int col = (kd * 16 + 8 * hi) ^ ((l31 & 7) << 3);
        bf16x8 kf0 = *(const bf16x8*)&Kt[cur][l31 * 64 + col];
        bf16x8 kf1 = *(const bf16x8*)&Kt[cur][(32 + l31) * 64 + col];
        mfma32(s0, kf0, qf[kd]);
        mfma32(s1, kf1, qf[kd]);
      }
      __builtin_amdgcn_s_setprio(0);
      fence16x2(s0, s1);
      // ---- causal mask (diag-band iters only; bounded sentinel)
      if (kv0 + 63 > qb0 + w * 32) {
        const int lim = qg - (kv0 + 4 * hi);
#pragma unroll
        for (int r = 0; r < 16; ++r) {
          const int C0 = (r & 3) + 8 * (r >> 2);
          if (C0 > lim) s0[r] = MNEG;
          if (C0 + 32 > lim) s1[r] = MNEG;
        }
      }
      // ---- p = exp2(s) via raw v_exp_f32
#pragma unroll
      for (int r = 0; r < 16; ++r) {
        s0[r] = __builtin_amdgcn_exp2f(s0[r]);
        s1[r] = __builtin_amdgcn_exp2f(s1[r]);
      }
      // ---- row sum (explicit tree) + cross-half
      float t8[8];
#pragma unroll
      for (int r = 0; r < 8; ++r)
        t8[r] = (s0[2 * r] + s0[2 * r + 1]) + (s1[2 * r] + s1[2 * r + 1]);
      float rs = ((t8[0] + t8[1]) + (t8[2] + t8[3])) +
                 ((t8[4] + t8[5]) + (t8[6] + t8[7]));
      lrun += rs + __shfl_xor(rs, 32, 64);
      // ---- pack P into B-frags via permlane32_swap (HW-verified order)
      i32x4 paw[4];
#pragma unroll
      for (int tl = 0; tl < 2; ++tl) {
        const f32x16& p = tl ? s1 : s0;
#pragma unroll
        for (int ks = 0; ks < 2; ++ks) {
          unsigned pk0 = cvtpk(p[8 * ks + 0], p[8 * ks + 1]);
          unsigned pk1 = cvtpk(p[8 * ks + 2], p[8 * ks + 3]);
          unsigned pk2 = cvtpk(p[8 * ks + 4], p[8 * ks + 5]);
          unsigned pk3 = cvtpk(p[8 * ks + 6], p[8 * ks + 7]);
          asm("v_permlane32_swap_b32 %0, %1" : "+v"(pk0), "+v"(pk2));
          asm("v_permlane32_swap_b32 %0, %1" : "+v"(pk1), "+v"(pk3));
          i32x4 A;
          A[0] = (int)pk0;
          A[1] = (int)pk1;
          A[2] = (int)pk2;
          A[3] = (int)pk3;
          paw[tl * 2 + ks] = A;
        }
      }
      asm volatile("s_nop 1");
      // ---- PV: o^T += V^T-frag x P-frag
      __builtin_amdgcn_s_setprio(1);
#pragma unroll
      for (int tl = 0; tl < 2; ++tl)
#pragma unroll
        for (int ks = 0; ks < 2; ++ks) {
          bf16x8 pa = __builtin_bit_cast(bf16x8, paw[tl * 2 + ks]);
          const int kvc = tl * 32 + ks * 16 + 8 * hi;
#pragma unroll
          for (int dt = 0; dt < 2; ++dt) {
            const int row = dt * 32 + l31;
            bf16x8 vf = *(const bf16x8*)&Vt[cur][row * 64 + (kvc ^ ((l31 & 7) << 3))];
            if (dt == 0) mfma32(o0, vf, pa);
            else         mfma32(o1, vf, pa);
          }
        }
      __builtin_amdgcn_s_setprio(0);
    }
    asm volatile("s_waitcnt vmcnt(0)" ::: "memory");
    __syncthreads();
  }
  fence16x2(o0, o1);
  const float inv = 1.f / lrun;
  u16* Yrow = Yg + (rb + qg) * 1024 + h64;
#pragma unroll
  for (int r = 0; r < 16; r += 2) {
    const int dbase = (r & 3) + 8 * (r >> 2) + 4 * hi;
    *(unsigned*)(Yrow + dbase) = cvtpk(o0[r] * inv, o0[r + 1] * inv);
    *(unsigned*)(Yrow + 32 + dbase) = cvtpk(o1[r] * inv, o1[r + 1] * inv);
  }
}

// ---------------- launch ----------------
extern "C" void kernel_launch(void* const* d_in, const int* in_sizes, int n_in,
                              void* d_out, int out_size, void* d_ws, size_t ws_size,
                              hipStream_t stream) {
  const float* x = (const float*)d_in[0];
  char* ws = (char*)d_ws;
  u16* xb = (u16*)ws;                          // attention Y (bf16)
  u16* wb = (u16*)(ws + (16u << 20));          // 8 x 131072 bf16 weights
  u16* Rq = (u16*)(ws + (18u << 20));          // [8192][128]
  u16* Rk = (u16*)(ws + (20u << 20));
  u16* Rv = (u16*)(ws + (22u << 20));
  u16* Qb = (u16*)(ws + (26u << 20));          // [8192][1024]
  u16* Kb = (u16*)(ws + (42u << 20));
  u16* VT = (u16*)(ws + (58u << 20));          // [64 bh][64 d][2048 t]
  float* Ry0 = (float*)(ws + (18u << 20));     // fp32 K-half partials (g3;
  float* Ry1 = (float*)(ws + (22u << 20));     //  Rq/Rk/Rv dead after attn)
  const int WSZ = 131072;
  const float SC = 0.18033688011112042f;       // 0.125 * log2(e)

  W8 wp;
  for (int i = 0; i < 8; ++i) wp.s[i] = (const float*)d_in[1 + i];
  cvt_w_kernel<<<1024, 256, 0, stream>>>(wp, wb);

  // R_{q,k,v} = x @ {q,k,v}A^T (M=8192, N=128, K=1024), CVTA fp32-x,
  // BM=32 + XCD-grouped linear grid: 768 blocks = 3/CU uniform
  G3 g1 = {};
  g1.A[0] = g1.A[1] = g1.A[2] = (const u16*)x;
  g1.B[0] = wb; g1.B[1] = wb + 2 * WSZ; g1.B[2] = wb + 4 * WSZ;
  g1.C[0] = Rq; g1.C[1] = Rk; g1.C[2] = Rv;
  g1.osc[0] = g1.osc[1] = g1.osc[2] = 1.f;
  g1.klen = 1024;
  gemm_nt<u16, 32, 1, true><<<dim3(768), 256, 0, stream>>>(g1, 8192, 128, 1024);

  // Q,K,V^T in ONE launch: Q scaled by SC; z=2 writes transposed V
  G3 g2 = {};
  g2.A[0] = Rq; g2.A[1] = Rk; g2.A[2] = Rv;
  g2.B[0] = wb + 1 * WSZ; g2.B[1] = wb + 3 * WSZ; g2.B[2] = wb + 5 * WSZ;
  g2.C[0] = Qb; g2.C[1] = Kb; g2.C[2] = VT;
  g2.osc[0] = SC; g2.osc[1] = 1.f; g2.osc[2] = 1.f;
  g2.vt[2] = 1;
  g2.klen = 128;
  gemm_nt<u16, 128, 0, false><<<dim3(64, 8, 3), 256, 0, stream>>>(g2, 8192, 1024, 128);

  // Y (into xb) = causal attention
  attn_kernel<<<dim3(1024), 256, 0, stream>>>(Qb, Kb, VT, xb);

  // Ry = Y @ cA^T split-K (2 fp32 partials), BM=32 -> 512 blocks = 2/CU
  G3 g3 = {};
  g3.A[0] = g3.A[1] = xb;
  g3.B[0] = g3.B[1] = wb + 6 * WSZ;
  g3.C[0] = Ry0; g3.C[1] = Ry1;
  g3.osc[0] = g3.osc[1] = 1.f;
  g3.koff[0] = 0; g3.koff[1] = 512;
  g3.klen = 512;
  gemm_nt<float, 32, 0, false><<<dim3(256, 1, 2), 256, 0, stream>>>(g3, 8192, 128, 1024);

  // out = (Ry0+Ry1) @ cB^T (fp32): CVTMODE=2 sums partials in-staging;
  // BM=64 -> 1024 blocks = 4/CU
  G3 g4 = {};
  g4.A[0] = (const u16*)Ry0; g4.A2[0] = Ry1;
  g4.B[0] = wb + 7 * WSZ;
  g4.C[0] = d_out;
  g4.osc[0] = 1.f;
  g4.klen = 128;
  gemm_nt<float, 64, 2, false><<<dim3(128, 8, 1), 256, 0, stream>>>(g4, 8192, 1024, 128);
}